// Round 6
// baseline (166.256 us; speedup 1.0000x reference)
//
#include <hip/hip_runtime.h>

#define BB 64
#define NN 512
#define FD 64

typedef short bf16x8 __attribute__((ext_vector_type(8)));
typedef float f32x4 __attribute__((ext_vector_type(4)));

__device__ __forceinline__ unsigned short f2bf(float f){
    unsigned u = __builtin_bit_cast(unsigned, f);
    u += 0x7fffu + ((u >> 16) & 1u);           // RNE
    return (unsigned short)(u >> 16);
}
__device__ __forceinline__ float bf2f(unsigned short h){
    unsigned u = ((unsigned)h) << 16;
    return __builtin_bit_cast(float, u);
}
__device__ __forceinline__ unsigned pkbf2(float a, float b){
    return (unsigned)f2bf(a) | ((unsigned)f2bf(b) << 16);
}
__device__ __forceinline__ float fast_tanh(float x){
    float e = __expf(2.0f * x);                 // inf -> 1, 0 -> -1: saturates correctly
    return 1.0f - 2.0f * __builtin_amdgcn_rcpf(e + 1.0f);
}
__device__ __forceinline__ bf16x8 pack8(float4 a, float4 b){
    bf16x8 r;
    r[0]=(short)f2bf(a.x); r[1]=(short)f2bf(a.y); r[2]=(short)f2bf(a.z); r[3]=(short)f2bf(a.w);
    r[4]=(short)f2bf(b.x); r[5]=(short)f2bf(b.y); r[6]=(short)f2bf(b.z); r[7]=(short)f2bf(b.w);
    return r;
}

// XW = X @ W via MFMA; emits XWh[b][n][f] and XWt[b][f][n] (bf16).
// W transposed per-block (16KB, L2-hot); block 0 computes colsum. (R2/R3-verified)
__global__ __launch_bounds__(256) void k_xw(const float* __restrict__ X,
                                            const float* __restrict__ W,
                                            const float* __restrict__ a,
                                            float* __restrict__ colsum,
                                            unsigned short* __restrict__ XWh,
                                            unsigned short* __restrict__ XWt){
    __shared__ float Wf[64][68];
    __shared__ float cpart[4][64];
    __shared__ unsigned short Xl[64][72];
    __shared__ unsigned short Wtl[64][72];
    __shared__ unsigned short Cl[64][72];    // C natural [n][f]
    __shared__ unsigned short ClT[64][72];   // C transposed [f][n]
    int t = threadIdx.x;
    int row0 = blockIdx.x * 64;
    int r = t >> 2, c0 = (t & 3) * 16;
    {
        const float4* srcW = (const float4*)&W[r*64 + c0];
        #pragma unroll
        for (int q = 0; q < 4; q++) *(float4*)&Wf[r][c0 + q*4] = srcW[q];
        const float4* srcX = (const float4*)&X[(row0 + r)*FD + c0];
        #pragma unroll
        for (int q = 0; q < 4; q++){
            float4 v = srcX[q];
            ushort4 h; h.x=f2bf(v.x); h.y=f2bf(v.y); h.z=f2bf(v.z); h.w=f2bf(v.w);
            *(ushort4*)&Xl[r][c0 + q*4] = h;
        }
    }
    if (blockIdx.x == 0){
        int d = t & 63, part = t >> 6;
        float s = 0.f;
        #pragma unroll
        for (int i = 0; i < 16; i++) s += a[(part*16 + i)*64 + d];
        cpart[part][d] = s;
    }
    __syncthreads();
    #pragma unroll
    for (int q = 0; q < 4; q++){
        ushort4 o;
        #pragma unroll
        for (int jj = 0; jj < 4; jj++)
            ((unsigned short*)&o)[jj] = f2bf(Wf[c0 + q*4 + jj][r]);
        *(ushort4*)&Wtl[r][c0 + q*4] = o;
    }
    if (blockIdx.x == 0 && t < 64)
        colsum[t] = cpart[0][t] + cpart[1][t] + cpart[2][t] + cpart[3][t];
    __syncthreads();
    int lane = t & 63, w = t >> 6, l15 = lane & 15, quad = lane >> 4;
    f32x4 acc[4] = {{0,0,0,0},{0,0,0,0},{0,0,0,0},{0,0,0,0}};
    #pragma unroll
    for (int ks = 0; ks < 2; ks++){
        bf16x8 af = *(const bf16x8*)&Xl[w*16 + l15][ks*32 + quad*8];
        #pragma unroll
        for (int nt = 0; nt < 4; nt++){
            bf16x8 bfr = *(const bf16x8*)&Wtl[nt*16 + l15][ks*32 + quad*8];
            acc[nt] = __builtin_amdgcn_mfma_f32_16x16x32_bf16(af, bfr, acc[nt], 0, 0, 0);
        }
    }
    #pragma unroll
    for (int nt = 0; nt < 4; nt++)
        #pragma unroll
        for (int rg = 0; rg < 4; rg++){
            unsigned short hb = f2bf(acc[nt][rg]);
            Cl [w*16 + quad*4 + rg][nt*16 + l15] = hb;
            ClT[nt*16 + l15][w*16 + quad*4 + rg] = hb;
        }
    __syncthreads();
    int b = blockIdx.x >> 3, n0 = (blockIdx.x & 7) * 64;
    {
        uint4 v0 = *(const uint4*)&Cl[r][c0];
        uint4 v1 = *(const uint4*)&Cl[r][c0 + 8];
        *(uint4*)&XWh[(row0 + r)*FD + c0]     = v0;
        *(uint4*)&XWh[(row0 + r)*FD + c0 + 8] = v1;
    }
    {
        uint4 v0 = *(const uint4*)&ClT[r][c0];
        uint4 v1 = *(const uint4*)&ClT[r][c0 + 8];
        *(uint4*)&XWt[(b*64 + r)*NN + n0 + c0]     = v0;
        *(uint4*)&XWt[(b*64 + r)*NN + n0 + c0 + 8] = v1;
    }
}

// Phase A as a standalone max-occupancy streaming GEMM (ZERO LDS):
// M[b][i][f] = bf16( (A_ @ XW)[i][f] * colsum[f] ), rowsum[b][i] = sum_j A_[i][j].
// 4 waves/block, each wave one 16-row strip; B-fragments (XWt) read per-MFMA from
// L2 (64KB/batch, XCD-local via grid(b,it)); A packed in-register (v5-verified path).
__global__ __launch_bounds__(256, 6) void k_phaseA(const float* __restrict__ A,
                                                   const unsigned short* __restrict__ XWh,
                                                   const unsigned short* __restrict__ XWt,
                                                   const float* __restrict__ colsum,
                                                   const int* __restrict__ Ni,
                                                   unsigned short* __restrict__ M,
                                                   float* __restrict__ rowsum){
    int t = threadIdx.x;
    int b = blockIdx.x, it = blockIdx.y;
    int i0 = it * 64;
    int lane = t & 63, w = t >> 6, l15 = lane & 15, quad = lane >> 4;
    int Nb = (Ni[1] == 0) ? Ni[2*b] : Ni[b];   // int64 vs int32 layout
    const float* Arow = A + (size_t)(b*NN + i0 + w*16 + l15)*NN + quad*8;
    const unsigned short* XWtb = XWt + (size_t)b*64*NN;
    const unsigned short* XWhb = XWh + (size_t)b*NN*FD;

    float4 pa[3][2];                           // depth-3 register prefetch of A
    #pragma unroll
    for (int s = 0; s < 3; s++){
        pa[s][0] = *(const float4*)&Arow[s*32];
        pa[s][1] = *(const float4*)&Arow[s*32 + 4];
    }
    f32x4 acc[4] = {{0,0,0,0},{0,0,0,0},{0,0,0,0},{0,0,0,0}};
    float rs = 0.f;
    #pragma unroll
    for (int s = 0; s < 16; s++){
        float4 v0 = pa[s % 3][0], v1 = pa[s % 3][1];
        if (s < 13){
            pa[s % 3][0] = *(const float4*)&Arow[(s + 3)*32];
            pa[s % 3][1] = *(const float4*)&Arow[(s + 3)*32 + 4];
        }
        rs += (v0.x + v0.y) + (v0.z + v0.w) + (v1.x + v1.y) + (v1.z + v1.w);
        bf16x8 af = pack8(v0, v1);
        #pragma unroll
        for (int nt = 0; nt < 4; nt++){        // swapped: D[f-local][i=l15]
            bf16x8 xa = *(const bf16x8*)&XWtb[(nt*16 + l15)*NN + s*32 + quad*8];
            acc[nt] = __builtin_amdgcn_mfma_f32_16x16x32_bf16(xa, af, acc[nt], 0, 0, 0);
        }
    }
    int irow = i0 + w*16 + l15;
    bool dg = irow < Nb;
    // in-wave rowsum over quads; merge the A_ diagonal's +1 here
    float rsum = rs;
    rsum += __shfl_xor(rsum, 16);
    rsum += __shfl_xor(rsum, 32);
    if (lane < 16){
        int i = i0 + w*16 + lane;
        rowsum[b*NN + i] = rsum + ((i < Nb) ? 1.f : 0.f);
    }
    // diag add (b64 reads from L2-hot XWh), colsum scale, M out (b64 stores)
    #pragma unroll
    for (int nt = 0; nt < 4; nt++){
        float4 cs4 = *(const float4*)&colsum[nt*16 + quad*4];
        ushort4 dh = *(const ushort4*)&XWhb[(size_t)irow*FD + nt*16 + quad*4];
        float m0 = (acc[nt][0] + (dg ? bf2f(dh.x) : 0.f)) * cs4.x;
        float m1 = (acc[nt][1] + (dg ? bf2f(dh.y) : 0.f)) * cs4.y;
        float m2 = (acc[nt][2] + (dg ? bf2f(dh.z) : 0.f)) * cs4.z;
        float m3 = (acc[nt][3] + (dg ? bf2f(dh.w) : 0.f)) * cs4.w;
        uint2 pk = { pkbf2(m0, m1), pkbf2(m2, m3) };
        *(uint2*)&M[((size_t)b*NN + irow)*FD + nt*16 + quad*4] = pk;
    }
}

// Phase B standalone, high occupancy: H = tanh(M @ XWh^T + rowsum*bias_a) @ XW + bias_W.
// Only LDS is the 9KB per-wave P strip (C->A transpose); all XW/M fragments from L2.
// All-swapped orientations exactly as v5 (verified): GEMM1 mfma(XWh_j, M_i),
// GEMM2 mfma(XWt_d, P_i) -> float4 H stores.
__global__ __launch_bounds__(256, 6) void k_phaseB(const unsigned short* __restrict__ XWh,
                                                   const unsigned short* __restrict__ XWt,
                                                   const unsigned short* __restrict__ M,
                                                   const float* __restrict__ rowsum,
                                                   const float* __restrict__ bias_a,
                                                   const float* __restrict__ bias_W,
                                                   float* __restrict__ H){
    __shared__ unsigned short Pl[4][16][72];   // per-wave P strip [i][j-local]
    int t = threadIdx.x;
    int b = blockIdx.x, it = blockIdx.y;
    int i0 = it * 64;
    int lane = t & 63, w = t >> 6, l15 = lane & 15, quad = lane >> 4;
    int irow = i0 + w*16 + l15;
    const unsigned short* XWtb = XWt + (size_t)b*64*NN;
    const unsigned short* XWhb = XWh + (size_t)b*NN*FD;
    const unsigned short* Mrow = M + ((size_t)b*NN + irow)*FD;

    bf16x8 maf[2];                             // M[i=l15][f-slice] -> GEMM1 B-operand
    maf[0] = *(const bf16x8*)&Mrow[quad*8];
    maf[1] = *(const bf16x8*)&Mrow[32 + quad*8];
    float rsum_l = rowsum[b*NN + irow];
    float4 bwv[4];
    #pragma unroll
    for (int dt = 0; dt < 4; dt++) bwv[dt] = *(const float4*)&bias_W[dt*16 + quad*4];

    f32x4 hacc[4] = {{0,0,0,0},{0,0,0,0},{0,0,0,0},{0,0,0,0}};
    #pragma unroll
    for (int jt = 0; jt < 8; jt++){
        #pragma unroll
        for (int nt = 0; nt < 4; nt++){        // GEMM1 swapped: att^T (j rows, i=l15 cols)
            float4 blv = *(const float4*)&bias_a[jt*64 + nt*16 + quad*4];
            f32x4 arg = { rsum_l*blv.x, rsum_l*blv.y, rsum_l*blv.z, rsum_l*blv.w };
            #pragma unroll
            for (int ks = 0; ks < 2; ks++){
                bf16x8 xh = *(const bf16x8*)&XWhb[(size_t)(jt*64 + nt*16 + l15)*FD + ks*32 + quad*8];
                arg = __builtin_amdgcn_mfma_f32_16x16x32_bf16(xh, maf[ks], arg, 0, 0, 0);
            }
            uint2 pk = { pkbf2(fast_tanh(arg[0]), fast_tanh(arg[1])),
                         pkbf2(fast_tanh(arg[2]), fast_tanh(arg[3])) };
            *(uint2*)&Pl[w][l15][nt*16 + quad*4] = pk;   // P[i=l15][j-local]
        }
        asm volatile("s_waitcnt lgkmcnt(0)" ::: "memory");
        __builtin_amdgcn_sched_barrier(0);
        #pragma unroll
        for (int ks = 0; ks < 2; ks++){        // GEMM2 swapped: H^T (d rows, i=l15 cols)
            bf16x8 pf = *(const bf16x8*)&Pl[w][l15][ks*32 + quad*8];
            #pragma unroll
            for (int dt = 0; dt < 4; dt++){
                bf16x8 xt = *(const bf16x8*)&XWtb[(size_t)(dt*16 + l15)*NN + jt*64 + ks*32 + quad*8];
                hacc[dt] = __builtin_amdgcn_mfma_f32_16x16x32_bf16(xt, pf, hacc[dt], 0, 0, 0);
            }
        }
    }
    float* Hrow = H + (size_t)(b*NN + irow)*FD;
    #pragma unroll
    for (int dt = 0; dt < 4; dt++){
        float4 hv = { hacc[dt][0] + bwv[dt].x, hacc[dt][1] + bwv[dt].y,
                      hacc[dt][2] + bwv[dt].z, hacc[dt][3] + bwv[dt].w };
        *(float4*)&Hrow[dt*16 + quad*4] = hv;
    }
}

extern "C" void kernel_launch(void* const* d_in, const int* in_sizes, int n_in,
                              void* d_out, int out_size, void* d_ws, size_t ws_size,
                              hipStream_t stream){
    const float* X      = (const float*)d_in[0];
    const float* A      = (const float*)d_in[1];
    const int*   N      = (const int*)  d_in[2];
    const float* W      = (const float*)d_in[3];
    const float* a      = (const float*)d_in[4];
    const float* bias_W = (const float*)d_in[5];
    const float* bias_a = (const float*)d_in[6];
    float* H = (float*)d_out;
    char* ws = (char*)d_ws;

    unsigned short* XWh    = (unsigned short*)(ws);                     // 4 MB
    unsigned short* XWt    = (unsigned short*)(ws + (4u<<20));          // 4 MB
    unsigned short* M      = (unsigned short*)(ws + (8u<<20));          // 4 MB
    float*          rowsum = (float*)(ws + (12u<<20));                  // 128 KB
    float*          colsum = (float*)(ws + (12u<<20) + (128u<<10));     // 256 B

    k_xw    <<<BB * NN / 64, 256, 0, stream>>>(X, W, a, colsum, XWh, XWt);
    k_phaseA<<<dim3(BB, 8), 256, 0, stream>>>(A, XWh, XWt, colsum, N, M, rowsum);
    k_phaseB<<<dim3(BB, 8), 256, 0, stream>>>(XWh, XWt, M, rowsum, bias_a, bias_W, H);
}

// Round 7
// 130.258 us; speedup vs baseline: 1.2764x; 1.2764x over previous
//
#include <hip/hip_runtime.h>

#define BB 64
#define NN 512
#define FD 64

typedef short bf16x8 __attribute__((ext_vector_type(8)));
typedef float f32x4 __attribute__((ext_vector_type(4)));

__device__ __forceinline__ unsigned short f2bf(float f){
    unsigned u = __builtin_bit_cast(unsigned, f);
    u += 0x7fffu + ((u >> 16) & 1u);           // RNE
    return (unsigned short)(u >> 16);
}
__device__ __forceinline__ float bf2f(unsigned short h){
    unsigned u = ((unsigned)h) << 16;
    return __builtin_bit_cast(float, u);
}
__device__ __forceinline__ unsigned pkbf2(float a, float b){
    return (unsigned)f2bf(a) | ((unsigned)f2bf(b) << 16);
}
__device__ __forceinline__ float fast_tanh(float x){
    float e = __expf(2.0f * x);                 // inf -> 1, 0 -> -1: saturates correctly
    return 1.0f - 2.0f * __builtin_amdgcn_rcpf(e + 1.0f);
}
__device__ __forceinline__ bf16x8 pack8(float4 a, float4 b){
    bf16x8 r;
    r[0]=(short)f2bf(a.x); r[1]=(short)f2bf(a.y); r[2]=(short)f2bf(a.z); r[3]=(short)f2bf(a.w);
    r[4]=(short)f2bf(b.x); r[5]=(short)f2bf(b.y); r[6]=(short)f2bf(b.z); r[7]=(short)f2bf(b.w);
    return r;
}
// async global->LDS DMA, 16B/lane: LDS dest = wave-uniform base + lane*16 (linear);
// per-lane global source (so swizzled LDS layouts = pre-swizzled source addresses).
__device__ __forceinline__ void gl2lds(const void* g, void* l){
    __builtin_amdgcn_global_load_lds(
        (const __attribute__((address_space(1))) unsigned int*)g,
        (__attribute__((address_space(3))) unsigned int*)l, 16, 0, 0);
}

// XW = X @ W via MFMA; emits XWh[b][n][f] and XWt[b][f][n] (bf16).
// W transposed per-block (16KB, L2-hot); block 0 computes colsum. (R2/R3-verified)
__global__ __launch_bounds__(256) void k_xw(const float* __restrict__ X,
                                            const float* __restrict__ W,
                                            const float* __restrict__ a,
                                            float* __restrict__ colsum,
                                            unsigned short* __restrict__ XWh,
                                            unsigned short* __restrict__ XWt){
    __shared__ float Wf[64][68];
    __shared__ float cpart[4][64];
    __shared__ unsigned short Xl[64][72];
    __shared__ unsigned short Wtl[64][72];
    __shared__ unsigned short Cl[64][72];    // C natural [n][f]
    __shared__ unsigned short ClT[64][72];   // C transposed [f][n]
    int t = threadIdx.x;
    int row0 = blockIdx.x * 64;
    int r = t >> 2, c0 = (t & 3) * 16;
    {
        const float4* srcW = (const float4*)&W[r*64 + c0];
        #pragma unroll
        for (int q = 0; q < 4; q++) *(float4*)&Wf[r][c0 + q*4] = srcW[q];
        const float4* srcX = (const float4*)&X[(row0 + r)*FD + c0];
        #pragma unroll
        for (int q = 0; q < 4; q++){
            float4 v = srcX[q];
            ushort4 h; h.x=f2bf(v.x); h.y=f2bf(v.y); h.z=f2bf(v.z); h.w=f2bf(v.w);
            *(ushort4*)&Xl[r][c0 + q*4] = h;
        }
    }
    if (blockIdx.x == 0){
        int d = t & 63, part = t >> 6;
        float s = 0.f;
        #pragma unroll
        for (int i = 0; i < 16; i++) s += a[(part*16 + i)*64 + d];
        cpart[part][d] = s;
    }
    __syncthreads();
    #pragma unroll
    for (int q = 0; q < 4; q++){
        ushort4 o;
        #pragma unroll
        for (int jj = 0; jj < 4; jj++)
            ((unsigned short*)&o)[jj] = f2bf(Wf[c0 + q*4 + jj][r]);
        *(ushort4*)&Wtl[r][c0 + q*4] = o;
    }
    if (blockIdx.x == 0 && t < 64)
        colsum[t] = cpart[0][t] + cpart[1][t] + cpart[2][t] + cpart[3][t];
    __syncthreads();
    int lane = t & 63, w = t >> 6, l15 = lane & 15, quad = lane >> 4;
    f32x4 acc[4] = {{0,0,0,0},{0,0,0,0},{0,0,0,0},{0,0,0,0}};
    #pragma unroll
    for (int ks = 0; ks < 2; ks++){
        bf16x8 af = *(const bf16x8*)&Xl[w*16 + l15][ks*32 + quad*8];
        #pragma unroll
        for (int nt = 0; nt < 4; nt++){
            bf16x8 bfr = *(const bf16x8*)&Wtl[nt*16 + l15][ks*32 + quad*8];
            acc[nt] = __builtin_amdgcn_mfma_f32_16x16x32_bf16(af, bfr, acc[nt], 0, 0, 0);
        }
    }
    #pragma unroll
    for (int nt = 0; nt < 4; nt++)
        #pragma unroll
        for (int rg = 0; rg < 4; rg++){
            unsigned short hb = f2bf(acc[nt][rg]);
            Cl [w*16 + quad*4 + rg][nt*16 + l15] = hb;
            ClT[nt*16 + l15][w*16 + quad*4 + rg] = hb;
        }
    __syncthreads();
    int b = blockIdx.x >> 3, n0 = (blockIdx.x & 7) * 64;
    {
        uint4 v0 = *(const uint4*)&Cl[r][c0];
        uint4 v1 = *(const uint4*)&Cl[r][c0 + 8];
        *(uint4*)&XWh[(row0 + r)*FD + c0]     = v0;
        *(uint4*)&XWh[(row0 + r)*FD + c0 + 8] = v1;
    }
    {
        uint4 v0 = *(const uint4*)&ClT[r][c0];
        uint4 v1 = *(const uint4*)&ClT[r][c0 + 8];
        *(uint4*)&XWt[(b*64 + r)*NN + n0 + c0]     = v0;
        *(uint4*)&XWt[(b*64 + r)*NN + n0 + c0 + 8] = v1;
    }
}

// v7: deep async A pipeline. Wave-private 4KB A chunks (16 rows x 64k f32) staged by
// global_load_lds (source-swizzled, cc^=row&7), double-buffered, counted vmcnt(4) waits
// (never 0 until the tail) -> ~64KB/CU in flight vs the ~3KB of register prefetch that
// capped every previous round at ~1 TB/s on the A stream. XWtL staged by DMA too.
// Phase B = v6-verified swapped math: xh from L2 (prefetched), GEMM2 B from XWtL,
// P strip reuses the drained A buffer. ONE __syncthreads total.
__global__ __launch_bounds__(512, 1) void k_fused(const float* __restrict__ A,
                                               const unsigned short* __restrict__ XWh,
                                               const unsigned short* __restrict__ XWt,
                                               const float* __restrict__ colsum,
                                               const int* __restrict__ Ni,
                                               const float* __restrict__ bias_a,
                                               const float* __restrict__ bias_W,
                                               float* __restrict__ H){
    __shared__ unsigned short XWtL[64][520];   // [f][n], row 1040B (bank drift 4/row)
    __shared__ float Abuf[8][2][1024];         // per-wave A chunk dbuf (swizzled)
    __shared__ float bl[512];                  // bias_a
    __shared__ float csl[64];                  // colsum
    int t = threadIdx.x;
    int b = blockIdx.x, it2 = blockIdx.y;
    int lane = t & 63, w = t >> 6, l15 = lane & 15, quad = lane >> 4;
    int tl = w >> 2, st = w & 3;
    int i0 = (it2 + 4*tl) * 64;
    int Nb = (Ni[1] == 0) ? Ni[2*b] : Ni[b];   // int64 vs int32 layout
    const unsigned short* XWtb = XWt + (size_t)b*64*NN;
    const unsigned short* XWhb = XWh + (size_t)b*NN*FD;

    // ---- stage XWtL via DMA: wave w stages rows w*8..w*8+8, 1 instr = 1 row (1KB) ----
    #pragma unroll
    for (int r8 = 0; r8 < 8; r8++){
        int row = w*8 + r8;
        gl2lds(&XWtb[(size_t)row*NN + lane*8], &XWtL[row][0]);
    }
    bl[t] = bias_a[t];
    if (t < 64) csl[t] = colsum[t];
    __syncthreads();                           // drains vmcnt -> XWtL visible to all

    // diag fragments (regular loads, oldest in FIFO before chunk DMAs)
    int irow = i0 + st*16 + l15;
    bool dg = irow < Nb;
    ushort4 dh[4];
    #pragma unroll
    for (int nt = 0; nt < 4; nt++)
        dh[nt] = *(const ushort4*)&XWhb[(size_t)irow*FD + nt*16 + quad*4];

    const float* Arowbase = A + (size_t)(b*NN + i0 + st*16)*NN;   // wave's 16 rows
    auto issue_chunk = [&](int c){
        #pragma unroll
        for (int q = 0; q < 4; q++){
            int r = q*4 + (lane >> 4);
            int cc = lane & 15;
            gl2lds(&Arowbase[(size_t)r*NN + c*64 + ((cc ^ (r & 7)) << 2)],
                   &Abuf[w][c & 1][q*256]);
        }
    };
    issue_chunk(0);
    issue_chunk(1);

    // ---- phase A: wave-private, vmcnt-counted pipeline over 8 chunks ----
    f32x4 acc[4] = {{0,0,0,0},{0,0,0,0},{0,0,0,0},{0,0,0,0}};
    float rs = 0.f;
    #pragma unroll
    for (int c = 0; c < 8; c++){
        if (c == 7) asm volatile("s_waitcnt vmcnt(0)" ::: "memory");
        else        asm volatile("s_waitcnt vmcnt(4)" ::: "memory");   // chunk c landed
        __builtin_amdgcn_sched_barrier(0);
        const float* Ab = &Abuf[w][c & 1][0];
        #pragma unroll
        for (int ks2 = 0; ks2 < 2; ks2++){
            int cc0 = ks2*8 + quad*2;
            float4 v0 = *(const float4*)&Ab[l15*64 + ((cc0       ^ (l15 & 7)) << 2)];
            float4 v1 = *(const float4*)&Ab[l15*64 + (((cc0 + 1) ^ (l15 & 7)) << 2)];
            rs += (v0.x + v0.y) + (v0.z + v0.w) + (v1.x + v1.y) + (v1.z + v1.w);
            bf16x8 af = pack8(v0, v1);
            int s = c*2 + ks2;
            #pragma unroll
            for (int nt = 0; nt < 4; nt++){    // swapped: D[f-local][i=l15]
                bf16x8 xa = *(const bf16x8*)&XWtL[nt*16 + l15][s*32 + quad*8];
                acc[nt] = __builtin_amdgcn_mfma_f32_16x16x32_bf16(xa, af, acc[nt], 0, 0, 0);
            }
        }
        if (c < 6){
            asm volatile("s_waitcnt lgkmcnt(0)" ::: "memory");  // ds_reads retired before overwrite
            __builtin_amdgcn_sched_barrier(0);
            issue_chunk(c + 2);
        }
    }
    // in-wave rowsum: every lane ends holding rowsum(row i = l15)
    float rsum = rs;
    rsum += __shfl_xor(rsum, 16);
    rsum += __shfl_xor(rsum, 32);
    float rsum_l = rsum + (dg ? 1.f : 0.f);
    // M strip (diag-add, colsum scale) -> P strip reusing drained Abuf[w][0]
    unsigned short* Ps = (unsigned short*)&Abuf[w][0][0];     // [16][72] layout
    #pragma unroll
    for (int nt = 0; nt < 4; nt++){
        float4 cs4 = *(const float4*)&csl[nt*16 + quad*4];
        float m0 = (acc[nt][0] + (dg ? bf2f(dh[nt].x) : 0.f)) * cs4.x;
        float m1 = (acc[nt][1] + (dg ? bf2f(dh[nt].y) : 0.f)) * cs4.y;
        float m2 = (acc[nt][2] + (dg ? bf2f(dh[nt].z) : 0.f)) * cs4.z;
        float m3 = (acc[nt][3] + (dg ? bf2f(dh[nt].w) : 0.f)) * cs4.w;
        uint2 pk = { pkbf2(m0, m1), pkbf2(m2, m3) };
        *(uint2*)&Ps[l15*72 + nt*16 + quad*4] = pk;
    }
    asm volatile("s_waitcnt lgkmcnt(0)" ::: "memory");
    __builtin_amdgcn_sched_barrier(0);
    bf16x8 maf[2];                             // M[i=l15][f-slice] -> GEMM1 B-operand
    maf[0] = *(const bf16x8*)&Ps[l15*72 + quad*8];
    maf[1] = *(const bf16x8*)&Ps[l15*72 + 32 + quad*8];

    // ---- phase B: 8 j-chunks, wave-private; xh from L2 with 1-deep prefetch ----
    bf16x8 xcur[8], xnxt[8];
    #pragma unroll
    for (int nt = 0; nt < 4; nt++)
        #pragma unroll
        for (int ks = 0; ks < 2; ks++)
            xcur[nt*2 + ks] = *(const bf16x8*)&XWhb[(size_t)(nt*16 + l15)*FD + ks*32 + quad*8];
    f32x4 hacc[4] = {{0,0,0,0},{0,0,0,0},{0,0,0,0},{0,0,0,0}};
    #pragma unroll
    for (int jt = 0; jt < 8; jt++){
        if (jt < 7){
            #pragma unroll
            for (int nt = 0; nt < 4; nt++)
                #pragma unroll
                for (int ks = 0; ks < 2; ks++)
                    xnxt[nt*2 + ks] = *(const bf16x8*)&XWhb[(size_t)((jt+1)*64 + nt*16 + l15)*FD + ks*32 + quad*8];
        }
        #pragma unroll
        for (int nt = 0; nt < 4; nt++){        // GEMM1 swapped: att^T (j rows, i=l15 cols)
            float4 blv = *(const float4*)&bl[jt*64 + nt*16 + quad*4];
            f32x4 arg = { rsum_l*blv.x, rsum_l*blv.y, rsum_l*blv.z, rsum_l*blv.w };
            arg = __builtin_amdgcn_mfma_f32_16x16x32_bf16(xcur[nt*2 + 0], maf[0], arg, 0, 0, 0);
            arg = __builtin_amdgcn_mfma_f32_16x16x32_bf16(xcur[nt*2 + 1], maf[1], arg, 0, 0, 0);
            uint2 pk = { pkbf2(fast_tanh(arg[0]), fast_tanh(arg[1])),
                         pkbf2(fast_tanh(arg[2]), fast_tanh(arg[3])) };
            *(uint2*)&Ps[l15*72 + nt*16 + quad*4] = pk;   // P[i=l15][j-local]
        }
        asm volatile("s_waitcnt lgkmcnt(0)" ::: "memory");
        __builtin_amdgcn_sched_barrier(0);
        #pragma unroll
        for (int ks = 0; ks < 2; ks++){        // GEMM2 swapped: H^T (d rows, i=l15 cols)
            bf16x8 pf = *(const bf16x8*)&Ps[l15*72 + ks*32 + quad*8];
            #pragma unroll
            for (int dt = 0; dt < 4; dt++){
                bf16x8 xt = *(const bf16x8*)&XWtL[dt*16 + l15][jt*64 + ks*32 + quad*8];
                hacc[dt] = __builtin_amdgcn_mfma_f32_16x16x32_bf16(xt, pf, hacc[dt], 0, 0, 0);
            }
        }
        #pragma unroll
        for (int q = 0; q < 8; q++) xcur[q] = xnxt[q];   // full unroll -> renames
    }
    // ---- store: f in-lane -> float4 stores ----
    float* Hrow = H + (size_t)(b*NN + irow)*FD;
    #pragma unroll
    for (int dt = 0; dt < 4; dt++){
        float4 bwv = *(const float4*)&bias_W[dt*16 + quad*4];
        float4 hv = { hacc[dt][0] + bwv.x, hacc[dt][1] + bwv.y,
                      hacc[dt][2] + bwv.z, hacc[dt][3] + bwv.w };
        *(float4*)&Hrow[dt*16 + quad*4] = hv;
    }
}

extern "C" void kernel_launch(void* const* d_in, const int* in_sizes, int n_in,
                              void* d_out, int out_size, void* d_ws, size_t ws_size,
                              hipStream_t stream){
    const float* X      = (const float*)d_in[0];
    const float* A      = (const float*)d_in[1];
    const int*   N      = (const int*)  d_in[2];
    const float* W      = (const float*)d_in[3];
    const float* a      = (const float*)d_in[4];
    const float* bias_W = (const float*)d_in[5];
    const float* bias_a = (const float*)d_in[6];
    float* H = (float*)d_out;
    char* ws = (char*)d_ws;

    unsigned short* XWh    = (unsigned short*)(ws);                    // 4 MB
    unsigned short* XWt    = (unsigned short*)(ws + (4u<<20));         // 4 MB
    float*          colsum = (float*)(ws + (8u<<20));                  // 256 B

    k_xw   <<<BB * NN / 64, 256, 0, stream>>>(X, W, a, colsum, XWh, XWt);
    k_fused<<<dim3(BB, 4), 512, 0, stream>>>(A, XWh, XWt, colsum, N, bias_a, bias_W, H);
}

// Round 8
// 122.832 us; speedup vs baseline: 1.3535x; 1.0605x over previous
//
#include <hip/hip_runtime.h>

#define BB 64
#define NN 512
#define FD 64

typedef short bf16x8 __attribute__((ext_vector_type(8)));
typedef float f32x4 __attribute__((ext_vector_type(4)));

__device__ __forceinline__ unsigned short f2bf(float f){
    unsigned u = __builtin_bit_cast(unsigned, f);
    u += 0x7fffu + ((u >> 16) & 1u);           // RNE
    return (unsigned short)(u >> 16);
}
__device__ __forceinline__ float bf2f(unsigned short h){
    unsigned u = ((unsigned)h) << 16;
    return __builtin_bit_cast(float, u);
}
__device__ __forceinline__ unsigned pkbf2(float a, float b){
    return (unsigned)f2bf(a) | ((unsigned)f2bf(b) << 16);
}
__device__ __forceinline__ float fast_tanh(float x){
    float e = __expf(2.0f * x);                 // inf -> 1, 0 -> -1: saturates correctly
    return 1.0f - 2.0f * __builtin_amdgcn_rcpf(e + 1.0f);
}
__device__ __forceinline__ bf16x8 pack8(float4 a, float4 b){
    bf16x8 r;
    r[0]=(short)f2bf(a.x); r[1]=(short)f2bf(a.y); r[2]=(short)f2bf(a.z); r[3]=(short)f2bf(a.w);
    r[4]=(short)f2bf(b.x); r[5]=(short)f2bf(b.y); r[6]=(short)f2bf(b.z); r[7]=(short)f2bf(b.w);
    return r;
}

// v8: v5 (best-measured) made fully self-contained -> ZERO workspace usage, ONE dispatch.
// Each block computes colsum in-block (a is 16KB, L3-hot; 2KB LDS partials) and builds
// its W^T fragments from global W via per-lane scalar gathers (16KB, L3-hot), then runs
// v5 verbatim: in-block XW both orientations (b64 packed writes), swapped phase A with
// depth-8 A prefetch, wave-private phase B, float4 H stores. Two barriers total.
__global__ __launch_bounds__(512, 1) void k_fused(const float* __restrict__ X,
                                               const float* __restrict__ A,
                                               const float* __restrict__ W,
                                               const float* __restrict__ a,
                                               const int* __restrict__ Ni,
                                               const float* __restrict__ bias_a,
                                               const float* __restrict__ bias_W,
                                               float* __restrict__ H){
    __shared__ unsigned short XWtL[64][520];   // [f][n], row 1040B (16B-mult)
    __shared__ unsigned short XWhL[512][72];   // [n][f], row 144B  (16B-mult)
    __shared__ unsigned short Pl[8][16][72];   // per-wave M/P strip [i][f or j]
    __shared__ float bl[512];                  // bias_a
    __shared__ float csl[64];                  // colsum
    __shared__ float cpart[8][64];             // colsum partials
    int t = threadIdx.x;
    int b = blockIdx.x, it2 = blockIdx.y;
    int lane = t & 63, w = t >> 6, l15 = lane & 15, quad = lane >> 4;
    int tl = w >> 2, st = w & 3;
    int i0 = (it2 + 4*tl) * 64;
    int Nb = (Ni[1] == 0) ? Ni[2*b] : Ni[b];   // int64 vs int32 layout
    const float* Xb = X + (size_t)b*NN*FD;
    const float* Arow = A + (size_t)(b*NN + i0 + st*16 + l15)*NN + quad*8;

    // ---- prologue: issue X fragment loads first (deepest need) ----
    float4 xv[8][2];                           // wave w computes XW rows [64w, 64w+64)
    #pragma unroll
    for (int rt = 0; rt < 4; rt++)
        #pragma unroll
        for (int ks = 0; ks < 2; ks++){
            const float* p = &Xb[(w*64 + rt*16 + l15)*FD + ks*32 + quad*8];
            xv[rt*2 + ks][0] = *(const float4*)p;
            xv[rt*2 + ks][1] = *(const float4*)(p + 4);
        }
    // colsum partials: 8 parts x 64 cols, 8 rows of 'a' each (coalesced, L3-hot)
    {
        int part = t >> 6, d = t & 63;
        float s = 0.f;
        #pragma unroll
        for (int i = 0; i < 8; i++) s += a[(part*8 + i)*64 + d];
        cpart[part][d] = s;
    }
    // W^T fragments straight from global W (16KB, L3-hot): wf[ft][ks][j] = W[c][d]
    bf16x8 wf[4][2];
    #pragma unroll
    for (int ft = 0; ft < 4; ft++)
        #pragma unroll
        for (int ks = 0; ks < 2; ks++){
            bf16x8 r;
            #pragma unroll
            for (int j = 0; j < 8; j++)
                r[j] = (short)f2bf(W[(ks*32 + quad*8 + j)*64 + ft*16 + l15]);
            wf[ft][ks] = r;
        }
    bl[t] = bias_a[t];
    __syncthreads();                           // barrier 1: cpart ready
    if (t < 64)
        csl[t] = ((cpart[0][t] + cpart[1][t]) + (cpart[2][t] + cpart[3][t]))
               + ((cpart[4][t] + cpart[5][t]) + (cpart[6][t] + cpart[7][t]));

    // ---- XW both orientations, packed b64 writes only (v5-verified) ----
    #pragma unroll
    for (int rt = 0; rt < 4; rt++){
        bf16x8 af0 = pack8(xv[rt*2][0],     xv[rt*2][1]);       // ks=0
        bf16x8 af1 = pack8(xv[rt*2 + 1][0], xv[rt*2 + 1][1]);   // ks=1
        f32x4 c[4]  = {{0,0,0,0},{0,0,0,0},{0,0,0,0},{0,0,0,0}};
        f32x4 ct[4] = {{0,0,0,0},{0,0,0,0},{0,0,0,0},{0,0,0,0}};
        #pragma unroll
        for (int nt = 0; nt < 4; nt++){
            c[nt]  = __builtin_amdgcn_mfma_f32_16x16x32_bf16(af0, wf[nt][0], c[nt], 0, 0, 0);
            c[nt]  = __builtin_amdgcn_mfma_f32_16x16x32_bf16(af1, wf[nt][1], c[nt], 0, 0, 0);
            ct[nt] = __builtin_amdgcn_mfma_f32_16x16x32_bf16(wf[nt][0], af0, ct[nt], 0, 0, 0);
            ct[nt] = __builtin_amdgcn_mfma_f32_16x16x32_bf16(wf[nt][1], af1, ct[nt], 0, 0, 0);
        }
        int n0 = w*64 + rt*16;
        #pragma unroll
        for (int nt = 0; nt < 4; nt++){        // XWtL[f][n]: n (=rg) in-lane -> b64
            uint2 pk = { pkbf2(c[nt][0], c[nt][1]), pkbf2(c[nt][2], c[nt][3]) };
            *(uint2*)&XWtL[nt*16 + l15][n0 + quad*4] = pk;
        }
        #pragma unroll
        for (int ft = 0; ft < 4; ft++){        // XWhL[n][f]: f (=rg) in-lane -> b64
            uint2 pk = { pkbf2(ct[ft][0], ct[ft][1]), pkbf2(ct[ft][2], ct[ft][3]) };
            *(uint2*)&XWhL[n0 + l15][ft*16 + quad*4] = pk;
        }
    }
    // A prefetch depth 8 (latency overlaps XW write drain + barrier)
    float4 pa[8][2];
    #pragma unroll
    for (int s = 0; s < 8; s++){
        pa[s][0] = *(const float4*)&Arow[s*32];
        pa[s][1] = *(const float4*)&Arow[s*32 + 4];
    }
    __syncthreads();                           // barrier 2: XW staged, csl ready

    // ---- phase A (swapped): Mt[f][i], i = l15, f = nt*16 + quad*4 + rg ----
    f32x4 acc[4] = {{0,0,0,0},{0,0,0,0},{0,0,0,0},{0,0,0,0}};
    float rs = 0.f;
    #pragma unroll
    for (int s = 0; s < 16; s++){
        float4 v0 = pa[s & 7][0], v1 = pa[s & 7][1];
        if (s < 8){                            // rotate prefetch 8 k-steps ahead
            pa[s & 7][0] = *(const float4*)&Arow[(s + 8)*32];
            pa[s & 7][1] = *(const float4*)&Arow[(s + 8)*32 + 4];
        }
        rs += (v0.x + v0.y) + (v0.z + v0.w) + (v1.x + v1.y) + (v1.z + v1.w);
        bf16x8 af = pack8(v0, v1);
        #pragma unroll
        for (int nt = 0; nt < 4; nt++){
            bf16x8 xa = *(const bf16x8*)&XWtL[nt*16 + l15][s*32 + quad*8];
            acc[nt] = __builtin_amdgcn_mfma_f32_16x16x32_bf16(xa, af, acc[nt], 0, 0, 0);
        }
    }
    int irow = i0 + st*16 + l15;               // this lane's i (output column)
    bool dg = irow < Nb;
    // diag add (b64 reads), colsum scale, M strip write (b64, row layout [i][f])
    #pragma unroll
    for (int nt = 0; nt < 4; nt++){
        float4 cs4 = *(const float4*)&csl[nt*16 + quad*4];
        ushort4 dh = *(const ushort4*)&XWhL[irow][nt*16 + quad*4];
        float m0 = (acc[nt][0] + (dg ? bf2f(dh.x) : 0.f)) * cs4.x;
        float m1 = (acc[nt][1] + (dg ? bf2f(dh.y) : 0.f)) * cs4.y;
        float m2 = (acc[nt][2] + (dg ? bf2f(dh.z) : 0.f)) * cs4.z;
        float m3 = (acc[nt][3] + (dg ? bf2f(dh.w) : 0.f)) * cs4.w;
        uint2 pk = { pkbf2(m0, m1), pkbf2(m2, m3) };
        *(uint2*)&Pl[w][l15][nt*16 + quad*4] = pk;
    }
    // in-wave rowsum: every lane ends holding rowsum(row i = l15)
    float rsum = rs;
    rsum += __shfl_xor(rsum, 16);
    rsum += __shfl_xor(rsum, 32);
    float rsum_l = rsum + (dg ? 1.f : 0.f);
    asm volatile("s_waitcnt lgkmcnt(0)" ::: "memory");
    __builtin_amdgcn_sched_barrier(0);
    bf16x8 maf[2];                             // M[i=l15][f-slice] -> GEMM1 B-operand
    maf[0] = *(const bf16x8*)&Pl[w][l15][quad*8];
    maf[1] = *(const bf16x8*)&Pl[w][l15][32 + quad*8];

    // ---- phase B: 8 j-chunks, wave-private, all-swapped ----
    f32x4 hacc[4] = {{0,0,0,0},{0,0,0,0},{0,0,0,0},{0,0,0,0}};
    float4 bwv[4];
    #pragma unroll
    for (int dt = 0; dt < 4; dt++) bwv[dt] = *(const float4*)&bias_W[dt*16 + quad*4];
    #pragma unroll
    for (int jt = 0; jt < 8; jt++){
        #pragma unroll
        for (int nt = 0; nt < 4; nt++){        // GEMM1 swapped: att^T (j rows, i=l15 cols)
            float4 blv = *(const float4*)&bl[jt*64 + nt*16 + quad*4];
            f32x4 arg = { rsum_l*blv.x, rsum_l*blv.y, rsum_l*blv.z, rsum_l*blv.w };
            #pragma unroll
            for (int ks = 0; ks < 2; ks++){
                bf16x8 xh = *(const bf16x8*)&XWhL[jt*64 + nt*16 + l15][ks*32 + quad*8];
                arg = __builtin_amdgcn_mfma_f32_16x16x32_bf16(xh, maf[ks], arg, 0, 0, 0);
            }
            uint2 pk = { pkbf2(fast_tanh(arg[0]), fast_tanh(arg[1])),
                         pkbf2(fast_tanh(arg[2]), fast_tanh(arg[3])) };
            *(uint2*)&Pl[w][l15][nt*16 + quad*4] = pk;   // P[i=l15][j-local], GEMM2-ready
        }
        asm volatile("s_waitcnt lgkmcnt(0)" ::: "memory");
        __builtin_amdgcn_sched_barrier(0);
        #pragma unroll
        for (int ks = 0; ks < 2; ks++){        // GEMM2 swapped: H^T (d rows, i=l15 cols)
            bf16x8 pf = *(const bf16x8*)&Pl[w][l15][ks*32 + quad*8];
            #pragma unroll
            for (int dt = 0; dt < 4; dt++){
                bf16x8 xt = *(const bf16x8*)&XWtL[dt*16 + l15][jt*64 + ks*32 + quad*8];
                hacc[dt] = __builtin_amdgcn_mfma_f32_16x16x32_bf16(xt, pf, hacc[dt], 0, 0, 0);
            }
        }
    }
    // ---- store: f in-lane -> float4 stores ----
    float* Hrow = H + (size_t)(b*NN + irow)*FD;
    #pragma unroll
    for (int dt = 0; dt < 4; dt++){
        float4 hv = { hacc[dt][0] + bwv[dt].x, hacc[dt][1] + bwv[dt].y,
                      hacc[dt][2] + bwv[dt].z, hacc[dt][3] + bwv[dt].w };
        *(float4*)&Hrow[dt*16 + quad*4] = hv;
    }
}

extern "C" void kernel_launch(void* const* d_in, const int* in_sizes, int n_in,
                              void* d_out, int out_size, void* d_ws, size_t ws_size,
                              hipStream_t stream){
    const float* X      = (const float*)d_in[0];
    const float* A      = (const float*)d_in[1];
    const int*   N      = (const int*)  d_in[2];
    const float* W      = (const float*)d_in[3];
    const float* a      = (const float*)d_in[4];
    const float* bias_W = (const float*)d_in[5];
    const float* bias_a = (const float*)d_in[6];
    float* H = (float*)d_out;
    (void)d_ws; (void)ws_size;                 // workspace intentionally unused

    k_fused<<<dim3(BB, 4), 512, 0, stream>>>(X, A, W, a, N, bias_a, bias_W, H);
}